// Round 11
// baseline (55.255 us; speedup 1.0000x reference)
//
#include <hip/hip_runtime.h>
#include <hip/hip_bf16.h>

// Shapes (fixed): D=1, S=64, A=128, P=K=6, T=80
#define NS 64
#define NA 128
#define NK 6
#define NT 80

// Output layout (flat concat, float):
//   waymo_valid  [S,T,A]        655360
//   waymo_trajs  [S,T,A,K,2]    7864320
//   waymo_scores [S,A,K]        49152
//   waymo_yaw    [S,T,A,K,1]    3932160
#define OFF_TRAJ   655360
#define OFF_SCORE  (655360 + 7864320)
#define OFF_YAW    (655360 + 7864320 + 49152)

typedef float nfloat4 __attribute__((ext_vector_type(4)));

// ===================== k_traj: pos -> trajs (output-major, 3KB runs) =====================
// block = (s, a-half 64 agents, t-chunk 8); grid (20, 64)
#define PW 388   // t-major LDS row width (f2): 384 rows + pad

__global__ __launch_bounds__(256) void k_traj(
    const float2* __restrict__ posIn,
    float*        __restrict__ out)
{
    const int s   = blockIdx.y;
    const int bx  = blockIdx.x;      // 0..19
    const int ah  = bx & 1;
    const int tc  = bx >> 1;         // 0..9
    const int a0  = ah * 64;
    const int t0  = tc * 8;
    const int tid = threadIdx.x;

    __shared__ float2 sPT[8][PW];    // [t-local][row], 24832 B

    const float2* pbase = posIn + ((size_t)s * NA + a0) * (NK * NT);

    // stage: 384 rows x 8 t = 1536 f4-equivalents? -> 1536 (f4 = 2 t of one row)
    // i: r = i>>2 (row 0..383), c = i&3 (t-pair 0..3)
    for (int i = tid; i < 1536; i += 256) {
        int r = i >> 2, c = i & 3;
        nfloat4 v = *(const nfloat4*)(pbase + (size_t)r * NT + t0 + 2 * c);
        sPT[2 * c + 0][r] = float2{v.x, v.y};
        sPT[2 * c + 1][r] = float2{v.z, v.w};
    }
    __syncthreads();

    // out: per t-local, 384 f2 = 192 f4 CONTIGUOUS (3072B run); 8 runs/block
    nfloat4* trajOut = (nfloat4*)(out + OFF_TRAJ);
    for (int o = tid; o < 1536; o += 256) {
        int t = o / 192, j = o - (o / 192) * 192;
        nfloat4 v = *(const nfloat4*)&sPT[t][2 * j];
        trajOut[(size_t)(s * NT + t0 + t) * 384 + ah * 192 + j] = v;
    }
}

// ===================== k_yaw: yaw -> yaw out + valid (output-major) =====================
// block = (s, a-half, t-chunk 8); grid (20, 64)
#define YW 392   // t-major LDS row width (f): 384 rows + pad

__global__ __launch_bounds__(256) void k_yaw(
    const int*   __restrict__ validIn,
    const float* __restrict__ yawIn,
    float*       __restrict__ out)
{
    const int s   = blockIdx.y;
    const int bx  = blockIdx.x;
    const int ah  = bx & 1;
    const int tc  = bx >> 1;
    const int a0  = ah * 64;
    const int t0  = tc * 8;
    const int tid = threadIdx.x;

    __shared__ float sYT[8][YW];     // [t-local][row], 12544 B

    const float* ybase = yawIn + ((size_t)s * NA + a0) * (NK * NT);

    // valid out (ah==0 blocks): 8 t x 32 f4 = exactly 256 threads; 512B runs
    if (ah == 0) {
        int t = tid >> 5, q = tid & 31;
        const int b = s * NA + 4 * q;
        nfloat4 v;
        v.x = (validIn[b + 0] != 0) ? 1.0f : 0.0f;
        v.y = (validIn[b + 1] != 0) ? 1.0f : 0.0f;
        v.z = (validIn[b + 2] != 0) ? 1.0f : 0.0f;
        v.w = (validIn[b + 3] != 0) ? 1.0f : 0.0f;
        ((nfloat4*)out)[(size_t)(s * NT + t0 + t) * 32 + q] = v;
    }

    // stage: 384 rows x 8 t; f4 = 4 consecutive t of one row
    for (int i = tid; i < 768; i += 256) {
        int r = i >> 1, c = i & 1;
        nfloat4 v = *(const nfloat4*)(ybase + (size_t)r * NT + t0 + 4 * c);
        sYT[4 * c + 0][r] = v.x;
        sYT[4 * c + 1][r] = v.y;
        sYT[4 * c + 2][r] = v.z;
        sYT[4 * c + 3][r] = v.w;
    }
    __syncthreads();

    // out: per t-local, 384 f = 96 f4 CONTIGUOUS (1536B run); 8 runs/block
    nfloat4* yawOut = (nfloat4*)(out + OFF_YAW);
    for (int o = tid; o < 768; o += 256) {
        int t = o / 96, j = o - (o / 96) * 96;
        nfloat4 v = *(const nfloat4*)&sYT[t][4 * j];
        yawOut[(size_t)(s * NT + t0 + t) * 192 + ah * 96 + j] = v;
    }
}

// ===================== k_score: softmax + NMS (verified R5 logic) =====================
// block = (s, 8 agents); 1024 blocks x 256 thr; runs last (pos L3-hot)
#define SPS 82   // f2 row stride

__global__ __launch_bounds__(256) void k_score(
    const int*    __restrict__ validIn,
    const float*  __restrict__ confIn,
    const float2* __restrict__ posIn,
    const float*  __restrict__ typeIn,
    float*        __restrict__ out)
{
    const int g   = blockIdx.x;
    const int tid = threadIdx.x;
    const int s   = g >> 4;
    const int a0  = (g & 15) * 8;

    __shared__ float2 sPos[48 * SPS];   // 31.5 KB

    const float2* pbase = posIn + ((size_t)s * NA + a0) * (NK * NT);

    // stage: 48 rows x 40 f4 = 1920 f4, contiguous 30 KB
    for (int i = tid; i < 1920; i += 256) {
        int r = i / 40, q = i - r * 40;
        nfloat4 v = *(const nfloat4*)(pbase + (size_t)r * NT + 2 * q);
        *(nfloat4*)&sPos[r * SPS + 2 * q] = v;
    }
    __syncthreads();

    const int la   = tid >> 5;    // agent 0..7
    const int lane = tid & 31;
    const int p    = lane >> 1;   // pair slot 0..15 (15 used)
    const int half = lane & 1;    // time half

    const size_t sa = (size_t)s * NA + a0 + la;
    const float th = 2.5f * typeIn[sa * 3 + 0]
                   + 1.0f * typeIn[sa * 3 + 1]
                   + 1.5f * typeIn[sa * 3 + 2];

    int pi, pj;
    if      (p < 5)  { pi = 0; pj = p + 1; }
    else if (p < 9)  { pi = 1; pj = p - 3; }
    else if (p < 12) { pi = 2; pj = p - 6; }
    else if (p < 14) { pi = 3; pj = p - 8; }
    else             { pi = 4; pj = 5;     }

    const int rI = la * NK + pi, rJ = la * NK + pj;
    float dsum = 0.f;
    for (int t = half * 40; t < half * 40 + 40; ++t) {
        float2 u = sPos[rI * SPS + t];
        float2 v = sPos[rJ * SPS + t];
        float dx = u.x - v.x, dy = u.y - v.y;
        dsum += sqrtf(dx * dx + dy * dy);
    }
    dsum += __shfl_xor(dsum, 1);
    const bool within = (dsum / 80.0f) < th;
    const bool predb  = (half == 0) && (p < 15) && within;
    unsigned long long bal = __ballot(predb);
    unsigned mask32 = (unsigned)(bal >> (tid & 32));  // this agent's 32 bits

    if (lane == 0) {
        // softmax over K=6 (stable) + renorm
        float c[NK];
        float mx = -3e38f;
        for (int q = 0; q < NK; ++q) { c[q] = confIn[sa * NK + q]; mx = fmaxf(mx, c[q]); }
        float ssum = 0.f;
        for (int q = 0; q < NK; ++q) { c[q] = expf(c[q] - mx); ssum += c[q]; }
        for (int q = 0; q < NK; ++q) c[q] /= ssum;
        ssum = 0.f;
        for (int q = 0; q < NK; ++q) ssum += c[q];
        for (int q = 0; q < NK; ++q) c[q] /= ssum;

        // stable descending argsort (selection; strict > keeps earliest on ties)
        int ord[NK]; bool used[NK];
        for (int q = 0; q < NK; ++q) used[q] = false;
        for (int st = 0; st < NK; ++st) {
            int best = 0; float bv = -3e38f;
            for (int q = 0; q < NK; ++q)
                if (!used[q] && c[q] > bv) { bv = c[q]; best = q; }
            used[best] = true; ord[st] = best;
        }

        float cur[NK];
        for (int q = 0; q < NK; ++q) cur[q] = c[q];

        if (validIn[sa] != 0) {
            for (int st = 0; st < NK; ++st) {
                int k = ord[st];
                float ck = cur[k];
                bool any = false;
                for (int j = 0; j < NK; ++j) {
                    if (j == k) continue;
                    int lo = j < k ? j : k;
                    int hi = j < k ? k : j;
                    int pidx = lo * 5 - (lo * (lo - 1)) / 2 + (hi - lo - 1);
                    if (((mask32 >> (2 * pidx)) & 1u) && (cur[j] > ck)) any = true;
                }
                if (any) cur[k] = 0.001f;
            }
        }

        // renormalize, then softmax(log(s)/0.5) == s^2 / sum(s^2)
        float tsum = 0.f;
        for (int q = 0; q < NK; ++q) tsum += cur[q];
        float w[NK]; float wsum = 0.f;
        for (int q = 0; q < NK; ++q) {
            float qq = cur[q] / tsum;
            w[q] = qq * qq; wsum += w[q];
        }
        float* outSc = out + OFF_SCORE;
        for (int q = 0; q < NK; ++q) outSc[sa * NK + q] = w[q] / wsum;
    }
}

extern "C" void kernel_launch(void* const* d_in, const int* in_sizes, int n_in,
                              void* d_out, int out_size, void* d_ws, size_t ws_size,
                              hipStream_t stream) {
    const int*    validIn = (const int*)d_in[0];
    const float*  confIn  = (const float*)d_in[1];
    const float2* posIn   = (const float2*)d_in[2];
    const float*  yawIn   = (const float*)d_in[3];
    const float*  typeIn  = (const float*)d_in[4];
    float* out = (float*)d_out;

    dim3 gridT(20, NS);   // 1280 blocks
    k_traj<<<gridT, 256, 0, stream>>>(posIn, out);
    dim3 gridY(20, NS);   // 1280 blocks
    k_yaw<<<gridY, 256, 0, stream>>>(validIn, yawIn, out);
    k_score<<<1024, 256, 0, stream>>>(validIn, confIn, posIn, typeIn, out);
}

// Round 12
// 35.809 us; speedup vs baseline: 1.5430x; 1.5430x over previous
//
#include <hip/hip_runtime.h>
#include <hip/hip_bf16.h>

// Shapes (fixed): D=1, S=64, A=128, P=K=6, T=80
#define NS 64
#define NA 128
#define NK 6
#define NT 80
#define THREADS 512
#define TILE_A 8
#define NROWS (TILE_A * NK)   // 48

// Output layout (flat concat, float):
//   waymo_valid  [S,T,A]        655360
//   waymo_trajs  [S,T,A,K,2]    7864320
//   waymo_scores [S,A,K]        49152
//   waymo_yaw    [S,T,A,K,1]    3932160
#define OFF_TRAJ   655360
#define OFF_SCORE  (655360 + 7864320)
#define OFF_YAW    (655360 + 7864320 + 49152)

#define PSTRIDE 82   // float2 row stride for pos (16B-aligned rows)
#define YSTRIDE 84   // float  row stride for yaw (16B-aligned rows)

typedef float nfloat4 __attribute__((ext_vector_type(4)));

__global__ __launch_bounds__(THREADS) void waymo_post_kernel(
    const int*    __restrict__ validIn,  // [S,A] (bool -> int32)
    const float*  __restrict__ confIn,   // [1,S,A,K]
    const float2* __restrict__ posIn,    // [1,S,A,K,T] float2
    const float*  __restrict__ yawIn,    // [1,S,A,K,T]
    const float*  __restrict__ typeIn,   // [S,A,3] one-hot
    float*        __restrict__ out)
{
    const int g   = blockIdx.x;          // 0..1023
    // XCD-aware swizzle: HW assigns XCD = g % 8 (8 XCDs). Give each XCD a
    // contiguous 128-work-item chunk (= 8 whole scenes) so adjacent a-tiles
    // of a scene (which write interleaved pieces of the same output t-rows)
    // share one L2. 1024 % 8 == 0 -> simple bijective form is valid.
    const int w   = ((g & 7) << 7) | (g >> 3);
    const int tid = threadIdx.x;
    const int s   = w >> 4;
    const int a0  = (w & 15) * TILE_A;

    __shared__ float2 sPos[NROWS * PSTRIDE];  // [row][t], 31.5 KB
    __shared__ float  sYaw[NROWS * YSTRIDE];  // [row][t], 15.75 KB

    const size_t sa0 = (size_t)s * NA + a0;
    const float2* pbase = posIn + sa0 * (NK * NT);
    const float*  ybase = yawIn + sa0 * (NK * NT);

    // ---- stage pos: 1920 float4, fully contiguous 30 KB range ----
    for (int i = tid; i < NROWS * (NT / 2); i += THREADS) {  // 40 float4/row
        int r = i / 40, q = i - r * 40;
        nfloat4 v = *(const nfloat4*)(pbase + (size_t)r * NT + 2 * q);
        *(nfloat4*)&sPos[r * PSTRIDE + 2 * q] = v;
    }
    // ---- stage yaw: 960 float4, contiguous 15 KB range ----
    for (int i = tid; i < NROWS * (NT / 4); i += THREADS) {  // 20 float4/row
        int r = i / 20, m = i - r * 20;
        nfloat4 v = *(const nfloat4*)(ybase + (size_t)r * NT + 4 * m);
        *(nfloat4*)&sYaw[r * YSTRIDE + 4 * m] = v;
    }
    __syncthreads();

    float* outSc = out + OFF_SCORE;

    // ---- score + NMS: waves 0..3 (32 lanes/agent); waves 4..7 skip ahead ----
    if (tid < 256) {
        const int la   = tid >> 5;
        const int lane = tid & 31;
        const int a    = a0 + la;
        const int p    = lane >> 1;   // pair slot 0..15 (15 used)
        const int half = lane & 1;    // time half

        const size_t sa = (size_t)s * NA + a;
        const float th = 2.5f * typeIn[sa * 3 + 0]
                       + 1.0f * typeIn[sa * 3 + 1]
                       + 1.5f * typeIn[sa * 3 + 2];

        int pi, pj;
        if      (p < 5)  { pi = 0; pj = p + 1; }
        else if (p < 9)  { pi = 1; pj = p - 3; }
        else if (p < 12) { pi = 2; pj = p - 6; }
        else if (p < 14) { pi = 3; pj = p - 8; }
        else             { pi = 4; pj = 5;     }

        const int rI = la * NK + pi, rJ = la * NK + pj;
        float dsum = 0.f;
        for (int t = half * 40; t < half * 40 + 40; ++t) {
            float2 u = sPos[rI * PSTRIDE + t];
            float2 v = sPos[rJ * PSTRIDE + t];
            float dx = u.x - v.x, dy = u.y - v.y;
            dsum += sqrtf(dx * dx + dy * dy);
        }
        dsum += __shfl_xor(dsum, 1);
        const bool within = (dsum / 80.0f) < th;
        const bool predb  = (half == 0) && (p < 15) && within;
        unsigned long long bal = __ballot(predb);
        unsigned mask32 = (unsigned)(bal >> (tid & 32));  // this agent's 32 bits

        if (lane == 0) {
            // softmax over K=6 (stable) + renorm
            float c[NK];
            float mx = -3e38f;
            for (int q = 0; q < NK; ++q) { c[q] = confIn[sa * NK + q]; mx = fmaxf(mx, c[q]); }
            float ssum = 0.f;
            for (int q = 0; q < NK; ++q) { c[q] = expf(c[q] - mx); ssum += c[q]; }
            for (int q = 0; q < NK; ++q) c[q] /= ssum;
            ssum = 0.f;
            for (int q = 0; q < NK; ++q) ssum += c[q];
            for (int q = 0; q < NK; ++q) c[q] /= ssum;

            // stable descending argsort (selection; strict > keeps earliest on ties)
            int ord[NK]; bool used[NK];
            for (int q = 0; q < NK; ++q) used[q] = false;
            for (int st = 0; st < NK; ++st) {
                int best = 0; float bv = -3e38f;
                for (int q = 0; q < NK; ++q)
                    if (!used[q] && c[q] > bv) { bv = c[q]; best = q; }
                used[best] = true; ord[st] = best;
            }

            float cur[NK];
            for (int q = 0; q < NK; ++q) cur[q] = c[q];

            if (validIn[sa] != 0) {
                for (int st = 0; st < NK; ++st) {
                    int k = ord[st];
                    float ck = cur[k];
                    bool any = false;
                    for (int j = 0; j < NK; ++j) {
                        if (j == k) continue;
                        int lo = j < k ? j : k;
                        int hi = j < k ? k : j;
                        int pidx = lo * 5 - (lo * (lo - 1)) / 2 + (hi - lo - 1);
                        if (((mask32 >> (2 * pidx)) & 1u) && (cur[j] > ck)) any = true;
                    }
                    if (any) cur[k] = 0.001f;
                }
            }

            // renormalize, then softmax(log(s)/0.5) == s^2 / sum(s^2)
            float tsum = 0.f;
            for (int q = 0; q < NK; ++q) tsum += cur[q];
            float w2[NK]; float wsum = 0.f;
            for (int q = 0; q < NK; ++q) {
                float qq = cur[q] / tsum;
                w2[q] = qq * qq; wsum += w2[q];
            }
            for (int q = 0; q < NK; ++q) outSc[sa * NK + q] = w2[q] / wsum;
        }
    }

    // ---- traj out: per t, 48 rows (float2) -> 24 float4 (384B runs), 1920 float4 ----
    nfloat4* trajOut = (nfloat4*)(out + OFF_TRAJ);
    for (int o = tid; o < NT * 24; o += THREADS) {
        int t = o / 24, j = o - (o / 24) * 24;
        float2 u = sPos[(2 * j + 0) * PSTRIDE + t];
        float2 w2 = sPos[(2 * j + 1) * PSTRIDE + t];
        nfloat4 v{u.x, u.y, w2.x, w2.y};
        size_t f4 = (((size_t)(s * NT + t) * NA + a0) * NK) >> 1;
        __builtin_nontemporal_store(v, trajOut + f4 + j);
    }
    // ---- yaw out: per t, 48 rows (float) -> 12 float4 (192B runs), 960 float4 ----
    nfloat4* yawOut = (nfloat4*)(out + OFF_YAW);
    for (int o = tid; o < NT * 12; o += THREADS) {
        int t = o / 12, j = o - (o / 12) * 12;
        nfloat4 v{sYaw[(4 * j + 0) * YSTRIDE + t],
                  sYaw[(4 * j + 1) * YSTRIDE + t],
                  sYaw[(4 * j + 2) * YSTRIDE + t],
                  sYaw[(4 * j + 3) * YSTRIDE + t]};
        size_t f4 = (((size_t)(s * NT + t) * NA + a0) * NK) >> 2;
        __builtin_nontemporal_store(v, yawOut + f4 + j);
    }
    // ---- valid out: even a-tiles write FULL 64B lines for 16 agents ----
    // (old version: every block wrote 32B half-lines -> cross-XCD false sharing)
    if ((w & 1) == 0 && tid < NT * 4) {
        int t = tid >> 2, q = tid & 3;
        nfloat4 v;
        v.x = (validIn[sa0 + 4 * q + 0] != 0) ? 1.0f : 0.0f;
        v.y = (validIn[sa0 + 4 * q + 1] != 0) ? 1.0f : 0.0f;
        v.z = (validIn[sa0 + 4 * q + 2] != 0) ? 1.0f : 0.0f;
        v.w = (validIn[sa0 + 4 * q + 3] != 0) ? 1.0f : 0.0f;
        size_t f4 = ((size_t)(s * NT + t) * NA + a0) >> 2;
        __builtin_nontemporal_store(v, (nfloat4*)out + f4 + q);
    }
}

extern "C" void kernel_launch(void* const* d_in, const int* in_sizes, int n_in,
                              void* d_out, int out_size, void* d_ws, size_t ws_size,
                              hipStream_t stream) {
    const int*    validIn = (const int*)d_in[0];
    const float*  confIn  = (const float*)d_in[1];
    const float2* posIn   = (const float2*)d_in[2];
    const float*  yawIn   = (const float*)d_in[3];
    const float*  typeIn  = (const float*)d_in[4];
    float* out = (float*)d_out;

    waymo_post_kernel<<<NS * (NA / TILE_A), THREADS, 0, stream>>>(
        validIn, confIn, posIn, yawIn, typeIn, out);
}